// Round 3
// baseline (283.299 us; speedup 1.0000x reference)
//
#include <hip/hip_runtime.h>
#include <math.h>

// SVD++ scoring, R9: XCD-sliced gather + LDS compaction queue + 16-deep batch.
// R8 proved slicing halves L2-fill traffic (FETCH 93->49 MB) but its
// compaction serialized the gathers (MLP ~1-2) -> latency-bound, 83.7 us.
// R9 restores R6/R7's proven 16-deep gather batch on top of the slicing:
//   - wave scans CHUNK=512 consecutive positions (8 coalesced nt idx loads),
//   - qualifying lanes (idx&7 == slice) binary-search their segment and
//     append packed (seg<<17|idx) into an LDS queue (ballot + prefix-popc),
//   - queue drains in 64-row batches: 16 back-to-back float4 gathers
//     (sched_barrier-pinned, all L2-hit on the XCD's 3.2 MB slice),
//   - segments are non-decreasing along the queue -> per-16-lane-group
//     run detection; each run flushes dot(acc, i_seg)/sqrt(n) via 4 shfls
//     + one atomicAdd(out[seg]).
// Streams that would evict the resident slice (flat indices x8, per-run
// item rows) are nontemporal. bid&7 = slice -> round-robin XCD mapping
// keeps each slice on one XCD's L2 [perf heuristic].
// Final kernel adds u.i + biases; out doubles as accumulator (memset 0).

typedef float f4 __attribute__((ext_vector_type(4)));

#define CHUNK  512   // positions scanned per wave
#define SUPERS 8     // CHUNK / 64
#define QCAP   512   // worst case: every position qualifies
#define WPB    4     // waves per block

template <typename T>
__device__ __forceinline__ T ntload(const T* p) {
    return __builtin_nontemporal_load(const_cast<T*>(p));
}

// ---- drain-phase macros -------------------------------------------------
// group = 16 lanes (sub = lane>>4); group handles queue entries
// tb + 16*sub + d, d = 0..15 (contiguous -> long seg runs).

#define GIDX(d) const int pk##d = __shfl(pk, 16 * sub + (d), 64);
#define GVAL(d) const f4 v##d = impv[(size_t)(pk##d & 0x1FFFF) * 16 + l16];

#define FLUSH()                                                              \
    {                                                                        \
        float p = acc.x * i4.x + acc.y * i4.y + acc.z * i4.z + acc.w * i4.w; \
        p += __shfl_xor(p, 1, 64);                                           \
        p += __shfl_xor(p, 2, 64);                                           \
        p += __shfl_xor(p, 4, 64);                                           \
        p += __shfl_xor(p, 8, 64);                                           \
        const int s0 = offsets[cur];                                         \
        const int e0 = (cur + 1 < B) ? offsets[cur + 1] : N;                 \
        const float invn = 1.0f / sqrtf((float)(e0 - s0));                   \
        if (l16 == 0) atomicAdd(&out[cur], p * invn);                        \
    }

#define ASTEP(d)                                                             \
    {                                                                        \
        const int e = tb + 16 * sub + (d);                                   \
        if (e < qcount) {                                                    \
            const int sd = pk##d >> 17;                                      \
            if (sd != cur) {                                                 \
                FLUSH();                                                     \
                cur = sd;                                                    \
                i4  = ntload(&item4[(size_t)item_ids[cur] * 16 + l16]);      \
                acc = (f4)(0.f);                                             \
            }                                                                \
            acc += v##d;                                                     \
        }                                                                    \
    }

__global__ __launch_bounds__(256, 1) void svdpp_gather(
    const int* __restrict__ item_ids,
    const int* __restrict__ offsets,
    const int* __restrict__ flat_implicit,
    const float* __restrict__ item_emb,
    const float* __restrict__ imp_emb,
    float* __restrict__ out,
    int B, int N)
{
    __shared__ int lq[WPB][QCAP];

    const int k    = blockIdx.x & 7;          // slice id == XCD id heuristic
    const int wave = threadIdx.x >> 6;
    const int lane = threadIdx.x & 63;
    const int base = ((blockIdx.x >> 3) * WPB + wave) * CHUNK;
    if (base >= N) return;

    const int sub = lane >> 4;
    const int l16 = lane & 15;

    int* const myq = lq[wave];
    int qcount = 0;

    // ---- scan phase: filter + compact 512 positions into the queue ----
    #pragma unroll
    for (int s = 0; s < SUPERS; ++s) {
        const int pos = base + s * 64 + lane;
        int  idx  = 0;
        int  seg  = 0;
        bool qok  = false;
        if (pos < N) {
            idx = ntload(&flat_implicit[pos]);   // coalesced, L2-bypassing
            qok = ((idx & 7) == k);
            if (qok) {
                int lo = 0, hi = B;              // upper_bound(offsets,pos)-1
                while (lo < hi) {
                    const int mid = (lo + hi) >> 1;
                    if (offsets[mid] <= pos) lo = mid + 1; else hi = mid;
                }
                seg = lo - 1;
            }
        }
        const unsigned long long m = __ballot(qok);
        const int rank = __popcll(m & ((1ull << lane) - 1ull));
        if (qok) myq[qcount + rank] = (seg << 17) | idx;
        qcount += __popcll(m);
    }

    // queue written by this wave only; make writes visible before reads
    asm volatile("s_waitcnt lgkmcnt(0)" ::: "memory");

    // ---- drain phase: 64-row batches of dense, L2-resident gathers ----
    const f4* impv  = (const f4*)imp_emb;
    const f4* item4 = (const f4*)item_emb;

    for (int tb = 0; tb < qcount; tb += 64) {
        const int ec = min(tb + lane, qcount - 1);   // clamped entry
        const int pk = myq[ec];

        GIDX(0)  GIDX(1)  GIDX(2)  GIDX(3)
        GIDX(4)  GIDX(5)  GIDX(6)  GIDX(7)
        GIDX(8)  GIDX(9)  GIDX(10) GIDX(11)
        GIDX(12) GIDX(13) GIDX(14) GIDX(15)

        GVAL(0)  GVAL(1)  GVAL(2)  GVAL(3)
        GVAL(4)  GVAL(5)  GVAL(6)  GVAL(7)
        GVAL(8)  GVAL(9)  GVAL(10) GVAL(11)
        GVAL(12) GVAL(13) GVAL(14) GVAL(15)

        // pin: all 16 gathers in flight before any consumption
        __builtin_amdgcn_sched_barrier(0);

        const bool hasAny = (tb + 16 * sub) < qcount;
        int cur = pk0 >> 17;
        f4  acc = (f4)(0.f);
        f4  i4  = (f4)(0.f);
        if (hasAny) i4 = ntload(&item4[(size_t)item_ids[cur] * 16 + l16]);

        ASTEP(0)  ASTEP(1)  ASTEP(2)  ASTEP(3)
        ASTEP(4)  ASTEP(5)  ASTEP(6)  ASTEP(7)
        ASTEP(8)  ASTEP(9)  ASTEP(10) ASTEP(11)
        ASTEP(12) ASTEP(13) ASTEP(14) ASTEP(15)

        if (hasAny) FLUSH();
    }
}

__global__ __launch_bounds__(256, 1) void svdpp_final(
    const int* __restrict__ user_ids,
    const int* __restrict__ item_ids,
    const int* __restrict__ offsets,
    const float* __restrict__ user_emb,
    const float* __restrict__ item_emb,
    const float* __restrict__ user_bias,
    const float* __restrict__ item_bias,
    const float* __restrict__ global_bias,
    float* __restrict__ out,
    int B, int N)
{
    const int l16 = threadIdx.x & 15;
    const int b   = blockIdx.x * 16 + (threadIdx.x >> 4);
    if (b >= B) return;

    const int user = user_ids[b];
    const int item = item_ids[b];

    const f4 u4 = ((const f4*)user_emb)[(size_t)user * 16 + l16];
    const f4 i4 = ((const f4*)item_emb)[(size_t)item * 16 + l16];

    float p = u4.x * i4.x + u4.y * i4.y + u4.z * i4.z + u4.w * i4.w;
    p += __shfl_xor(p, 1, 64);
    p += __shfl_xor(p, 2, 64);
    p += __shfl_xor(p, 4, 64);
    p += __shfl_xor(p, 8, 64);

    if (l16 == 0) {
        // gather kernel already applied 1/sqrt(n) per flush
        out[b] += p + user_bias[user] + item_bias[item] + global_bias[0];
    }
}

extern "C" void kernel_launch(void* const* d_in, const int* in_sizes, int n_in,
                              void* d_out, int out_size, void* d_ws, size_t ws_size,
                              hipStream_t stream) {
    const int*   user_ids      = (const int*)  d_in[0];
    const int*   item_ids      = (const int*)  d_in[1];
    const int*   offsets       = (const int*)  d_in[2];
    const int*   flat_implicit = (const int*)  d_in[3];
    const float* user_emb      = (const float*)d_in[4];
    const float* item_emb      = (const float*)d_in[5];
    const float* imp_emb       = (const float*)d_in[6];
    const float* user_bias     = (const float*)d_in[7];
    const float* item_bias     = (const float*)d_in[8];
    const float* global_bias   = (const float*)d_in[9];
    float* out = (float*)d_out;

    const int B = in_sizes[0];
    const int N = in_sizes[3];

    hipMemsetAsync(out, 0, (size_t)B * sizeof(float), stream);

    const int nchunks = (N + CHUNK - 1) / CHUNK;
    const int blocks  = 8 * ((nchunks + WPB - 1) / WPB);
    svdpp_gather<<<blocks, WPB * 64, 0, stream>>>(
        item_ids, offsets, flat_implicit, item_emb, imp_emb, out, B, N);

    svdpp_final<<<(B + 15) / 16, 256, 0, stream>>>(
        user_ids, item_ids, offsets, user_emb, item_emb,
        user_bias, item_bias, global_bias, out, B, N);
}

// Round 4
// 198.447 us; speedup vs baseline: 1.4276x; 1.4276x over previous
//
#include <hip/hip_runtime.h>
#include <math.h>

// SVD++ scoring, R10: counting-sort by (idx&7) into workspace, then dense
// XCD-resident gather with R7's proven 16-deep MLP.
// Evidence: R6/R7 (different instr counts, same FETCH 93MB) both ~42us ->
// fabric-byte-bound at ~2.3 TB/s random. R8/R9 proved idx&7 slicing cuts
// FETCH to ~45MB but their fused filtering serialized the memory pipeline.
// R10 separates concerns:
//   K1 scatter: one binary search per lane, block-aggregated bucket append
//       (8 atomicAdds per 1024-thr block), contiguous per-bucket entries
//       packed as (seg<<17)|idx  [B<=2^14, I<2^17].
//   K2 gather: bucket k on XCD k (bid&7), grid-strided waves, 64 entries
//       per batch: coalesced pk load -> shfl distribute -> 16 back-to-back
//       float4 gathers (sched_barrier) on the 3.2MB L2-resident slice ->
//       run-detect -> dot(acc,i)*invn -> atomicAdd(accum[seg]).
//   K3 final: out[b] = accum[b] + u.i + biases.
// ws layout: [0,32) counts, [64, 64+4B) accum, [65792, ...) 8 buckets.

typedef float f4 __attribute__((ext_vector_type(4)));

#define SC_THREADS 1024
#define SC_WAVES   16
#define WPB        4      // gather waves per block
#define ACCUM_OFF  64
#define BUCKET_OFF 65792

template <typename T>
__device__ __forceinline__ T ntload(const T* p) {
    return __builtin_nontemporal_load(const_cast<T*>(p));
}

// ---------------- K1: bucket scatter ----------------
__global__ __launch_bounds__(SC_THREADS, 1) void svdpp_scatter(
    const int* __restrict__ offsets,
    const int* __restrict__ flat_implicit,
    int* __restrict__ counts,
    int* __restrict__ buckets,
    int cap, int B, int N)
{
    __shared__ int wcnt[SC_WAVES][8];
    __shared__ int wbase[SC_WAVES][8];

    const int tid  = threadIdx.x;
    const int wave = tid >> 6;
    const int lane = tid & 63;
    const int pos  = blockIdx.x * SC_THREADS + tid;
    const bool valid = pos < N;

    int idx = 0, seg = 0, bucket = -1;
    if (valid) {
        idx    = flat_implicit[pos];
        bucket = idx & 7;
        int lo = 0, hi = B;               // upper_bound(offsets, pos) - 1
        while (lo < hi) {
            const int mid = (lo + hi) >> 1;
            if (offsets[mid] <= pos) lo = mid + 1; else hi = mid;
        }
        seg = lo - 1;
    }
    const int pk = (seg << 17) | idx;

    int myrank = 0;
    const unsigned long long mlt = (1ull << lane) - 1ull;
    #pragma unroll
    for (int k = 0; k < 8; ++k) {
        const unsigned long long m = __ballot(bucket == k);
        if (bucket == k) myrank = __popcll(m & mlt);
        if (lane == 0) wcnt[wave][k] = __popcll(m);
    }
    __syncthreads();

    if (tid < 8) {                        // one thread per bucket
        const int k = tid;
        int tot = 0;
        #pragma unroll
        for (int w = 0; w < SC_WAVES; ++w) tot += wcnt[w][k];
        int base = atomicAdd(&counts[k], tot);
        #pragma unroll
        for (int w = 0; w < SC_WAVES; ++w) {
            wbase[w][k] = base;
            base += wcnt[w][k];
        }
    }
    __syncthreads();

    if (valid) {
        const int slot = wbase[wave][bucket] + myrank;
        if (slot < cap)                   // safety only; cap >> max count
            buckets[(size_t)bucket * cap + slot] = pk;
    }
}

// ---------------- K2: dense resident gather ----------------
#define GIDX(d) const int pk##d = __shfl(pk, 16 * sub + (d), 64);
#define GVAL(d) const f4 v##d = impv[(size_t)(pk##d & 0x1FFFF) * 16 + l16];

#define FLUSH()                                                              \
    {                                                                        \
        float p = acc.x * i4.x + acc.y * i4.y + acc.z * i4.z + acc.w * i4.w; \
        p += __shfl_xor(p, 1, 64);                                           \
        p += __shfl_xor(p, 2, 64);                                           \
        p += __shfl_xor(p, 4, 64);                                           \
        p += __shfl_xor(p, 8, 64);                                           \
        const int s0 = offsets[cur];                                         \
        const int e0 = (cur + 1 < B) ? offsets[cur + 1] : N;                 \
        const float invn = 1.0f / sqrtf((float)(e0 - s0));                   \
        if (l16 == 0) atomicAdd(&accum[cur], p * invn);                      \
    }

#define ASTEP(d)                                                             \
    {                                                                        \
        const int e = tb + 16 * sub + (d);                                   \
        if (e < cnt) {                                                       \
            const int sd = pk##d >> 17;                                      \
            if (sd != cur) {                                                 \
                FLUSH();                                                     \
                cur = sd;                                                    \
                i4  = ntload(&item4[(size_t)item_ids[cur] * 16 + l16]);      \
                acc = (f4)(0.f);                                             \
            }                                                                \
            acc += v##d;                                                     \
        }                                                                    \
    }

__global__ __launch_bounds__(256, 1) void svdpp_gather(
    const int* __restrict__ item_ids,
    const int* __restrict__ offsets,
    const float* __restrict__ item_emb,
    const float* __restrict__ imp_emb,
    const int* __restrict__ counts,
    const int* __restrict__ buckets,
    float* __restrict__ accum,
    int cap, int B, int N)
{
    const int k    = blockIdx.x & 7;      // bucket id == XCD heuristic
    const int j    = blockIdx.x >> 3;
    const int wave = threadIdx.x >> 6;
    const int lane = threadIdx.x & 63;
    const int sub  = lane >> 4;
    const int l16  = lane & 15;

    int cnt = counts[k];
    if (cnt > cap) cnt = cap;
    const int* __restrict__ bq = buckets + (size_t)k * cap;

    const int wid = j * WPB + wave;           // wave index within bucket
    const int nw  = (gridDim.x >> 3) * WPB;   // waves per bucket

    const f4* impv  = (const f4*)imp_emb;
    const f4* item4 = (const f4*)item_emb;

    for (int tb = wid * 64; tb < cnt; tb += nw * 64) {
        const int ec = min(tb + lane, cnt - 1);
        const int pk = ntload(&bq[ec]);       // coalesced entry load

        GIDX(0)  GIDX(1)  GIDX(2)  GIDX(3)
        GIDX(4)  GIDX(5)  GIDX(6)  GIDX(7)
        GIDX(8)  GIDX(9)  GIDX(10) GIDX(11)
        GIDX(12) GIDX(13) GIDX(14) GIDX(15)

        GVAL(0)  GVAL(1)  GVAL(2)  GVAL(3)
        GVAL(4)  GVAL(5)  GVAL(6)  GVAL(7)
        GVAL(8)  GVAL(9)  GVAL(10) GVAL(11)
        GVAL(12) GVAL(13) GVAL(14) GVAL(15)

        // all 16 gathers in flight before any consumption
        __builtin_amdgcn_sched_barrier(0);

        const bool hasAny = (tb + 16 * sub) < cnt;
        int cur = pk0 >> 17;
        f4  acc = (f4)(0.f);
        f4  i4  = (f4)(0.f);
        if (hasAny) i4 = ntload(&item4[(size_t)item_ids[cur] * 16 + l16]);

        ASTEP(0)  ASTEP(1)  ASTEP(2)  ASTEP(3)
        ASTEP(4)  ASTEP(5)  ASTEP(6)  ASTEP(7)
        ASTEP(8)  ASTEP(9)  ASTEP(10) ASTEP(11)
        ASTEP(12) ASTEP(13) ASTEP(14) ASTEP(15)

        if (hasAny) FLUSH();
    }
}

// ---------------- K3: epilogue ----------------
__global__ __launch_bounds__(256, 1) void svdpp_final(
    const int* __restrict__ user_ids,
    const int* __restrict__ item_ids,
    const float* __restrict__ user_emb,
    const float* __restrict__ item_emb,
    const float* __restrict__ user_bias,
    const float* __restrict__ item_bias,
    const float* __restrict__ global_bias,
    const float* __restrict__ accum,
    float* __restrict__ out,
    int B)
{
    const int l16 = threadIdx.x & 15;
    const int b   = blockIdx.x * 16 + (threadIdx.x >> 4);
    if (b >= B) return;

    const int user = user_ids[b];
    const int item = item_ids[b];

    const f4 u4 = ((const f4*)user_emb)[(size_t)user * 16 + l16];
    const f4 i4 = ((const f4*)item_emb)[(size_t)item * 16 + l16];

    float p = u4.x * i4.x + u4.y * i4.y + u4.z * i4.z + u4.w * i4.w;
    p += __shfl_xor(p, 1, 64);
    p += __shfl_xor(p, 2, 64);
    p += __shfl_xor(p, 4, 64);
    p += __shfl_xor(p, 8, 64);

    if (l16 == 0)
        out[b] = p + accum[b] + user_bias[user] + item_bias[item]
               + global_bias[0];
}

extern "C" void kernel_launch(void* const* d_in, const int* in_sizes, int n_in,
                              void* d_out, int out_size, void* d_ws, size_t ws_size,
                              hipStream_t stream) {
    const int*   user_ids      = (const int*)  d_in[0];
    const int*   item_ids      = (const int*)  d_in[1];
    const int*   offsets       = (const int*)  d_in[2];
    const int*   flat_implicit = (const int*)  d_in[3];
    const float* user_emb      = (const float*)d_in[4];
    const float* item_emb      = (const float*)d_in[5];
    const float* imp_emb       = (const float*)d_in[6];
    const float* user_bias     = (const float*)d_in[7];
    const float* item_bias     = (const float*)d_in[8];
    const float* global_bias   = (const float*)d_in[9];
    float* out = (float*)d_out;

    const int B = in_sizes[0];
    const int N = in_sizes[3];

    int*   counts  = (int*)d_ws;
    float* accum   = (float*)((char*)d_ws + ACCUM_OFF);
    int*   buckets = (int*)((char*)d_ws + BUCKET_OFF);

    // per-bucket capacity from workspace size (expected ~N/8 + tiny jitter)
    long long avail = (long long)ws_size - BUCKET_OFF;
    int cap = (avail > 0) ? (int)(avail / (8 * sizeof(int))) : 0;
    if (cap > N) cap = N;

    // zero counts + accum in one memset
    hipMemsetAsync(d_ws, 0, ACCUM_OFF + (size_t)B * sizeof(float), stream);

    const int sblocks = (N + SC_THREADS - 1) / SC_THREADS;
    svdpp_scatter<<<sblocks, SC_THREADS, 0, stream>>>(
        offsets, flat_implicit, counts, buckets, cap, B, N);

    // ~1 batch per wave at expected bucket size N/8
    const int bpb = ((N / 8) + WPB * 64 - 1) / (WPB * 64);
    svdpp_gather<<<8 * bpb, WPB * 64, 0, stream>>>(
        item_ids, offsets, item_emb, imp_emb,
        counts, buckets, accum, cap, B, N);

    svdpp_final<<<(B + 15) / 16, 256, 0, stream>>>(
        user_ids, item_ids, user_emb, item_emb,
        user_bias, item_bias, global_bias, accum, out, B);
}

// Round 5
// 140.092 us; speedup vs baseline: 2.0222x; 1.4165x over previous
//
#include <hip/hip_runtime.h>
#include <math.h>

// SVD++ scoring, R11: R6 monolith (the verified-best structure, kernel ~41us)
// + rotated index prefetch.
// History: R7-R10 decompositions (position-parallel, XCD slicing, LDS queue,
// counting sort) all cut FETCH (93 -> 32 MB) yet all ran SLOWER (70-175us
// gather) -> the binding constraint is not fabric bytes; restructures lost
// the 16-deep in-flight gather codegen (R7/R10 VGPR=48/60 < the 64 needed)
// and exposed serial latency. So: keep R6's exact wave/b structure, 16-deep
// sched_barrier-pinned batch, and remove the ONE serial dependency that can
// be removed without touching the batch: the next super's 64 coalesced
// indices are loaded during the current super's gathers (rotated loop), so
// per-super critical path drops from (idx miss -> shfl -> gather miss) to
// (gather miss) for all supers after the first.
// dot(u + summed/norm, i) = u.i + (summed.i)/norm -> scalar wave reductions.

#define WAVES_PER_BLOCK 4

#define LOADIDX(d) const int idx##d = __shfl(my_idx, 4*(d) + sub, 64);
#define LOADVAL(d) const float4 v##d = impv[(size_t)idx##d * 16 + l16];
#define ACCUM(d)                                                         \
    if (super + 4*(d) + sub < end) {                                     \
        acc.x += v##d.x; acc.y += v##d.y;                                \
        acc.z += v##d.z; acc.w += v##d.w;                                \
    }

__global__ __launch_bounds__(256, 1) void svdpp_kernel(
    const int* __restrict__ user_ids,
    const int* __restrict__ item_ids,
    const int* __restrict__ offsets,
    const int* __restrict__ flat_implicit,
    const float* __restrict__ user_emb,
    const float* __restrict__ item_emb,
    const float* __restrict__ imp_emb,
    const float* __restrict__ user_bias,
    const float* __restrict__ item_bias,
    const float* __restrict__ global_bias,
    float* __restrict__ out,
    int B, int N)
{
    const int wave = threadIdx.x >> 6;
    const int lane = threadIdx.x & 63;
    const int b = blockIdx.x * WAVES_PER_BLOCK + wave;
    if (b >= B) return;

    const int sub = lane >> 4;   // 0..3: which row this lane helps load
    const int l16 = lane & 15;   // 0..15: which float4 of the row

    const int start = offsets[b];
    const int end   = (b + 1 < B) ? offsets[b + 1] : N;
    const int n     = end - start;

    const int user = user_ids[b];
    const int item = item_ids[b];

    // item-embedding fragment for this lane's 4 columns (broadcast across subs)
    const float4 i4 = ((const float4*)(item_emb + (size_t)item * 64))[l16];

    const float4* impv = (const float4*)imp_emb;
    float4 acc = make_float4(0.f, 0.f, 0.f, 0.f);

    // Rotated prefetch: my_idx for super s is loaded during super s-1
    // (or here, for the first super). Safe index when segment is empty.
    const int a0 = start + lane;
    int my_idx = flat_implicit[(a0 < end) ? a0
                               : ((start < end) ? start : 0)];

    // 64 rows per super-iteration; sub-group `sub` handles rows
    // super + 4*d + sub, d = 0..15. Out-of-range slots read a safe index
    // and are masked out of the accumulate, so all 16 gathers issue
    // unconditionally.
    for (int super = start; super < end; super += 64) {
        LOADIDX(0)  LOADIDX(1)  LOADIDX(2)  LOADIDX(3)
        LOADIDX(4)  LOADIDX(5)  LOADIDX(6)  LOADIDX(7)
        LOADIDX(8)  LOADIDX(9)  LOADIDX(10) LOADIDX(11)
        LOADIDX(12) LOADIDX(13) LOADIDX(14) LOADIDX(15)

        LOADVAL(0)  LOADVAL(1)  LOADVAL(2)  LOADVAL(3)
        LOADVAL(4)  LOADVAL(5)  LOADVAL(6)  LOADVAL(7)
        LOADVAL(8)  LOADVAL(9)  LOADVAL(10) LOADVAL(11)
        LOADVAL(12) LOADVAL(13) LOADVAL(14) LOADVAL(15)

        // prefetch next super's 64 indices; overlaps with the 16 gathers
        // and the accumulate chain below. Last iteration loads a cached
        // safe line (wasted but harmless).
        const int a2 = super + 64 + lane;
        const int my_idx_next = flat_implicit[(a2 < end) ? a2 : start];

        // nothing may cross: all 17 loads issue before any accumulate
        __builtin_amdgcn_sched_barrier(0);

        ACCUM(0)  ACCUM(1)  ACCUM(2)  ACCUM(3)
        ACCUM(4)  ACCUM(5)  ACCUM(6)  ACCUM(7)
        ACCUM(8)  ACCUM(9)  ACCUM(10) ACCUM(11)
        ACCUM(12) ACCUM(13) ACCUM(14) ACCUM(15)

        my_idx = my_idx_next;
    }

    // partial of summed·i (reduce over all 64 lanes: subs × columns)
    float ds = acc.x * i4.x + acc.y * i4.y + acc.z * i4.z + acc.w * i4.w;

    // partial of u·i: one column per lane
    const float u_c = user_emb[(size_t)user * 64 + lane];
    const float i_c = item_emb[(size_t)item * 64 + lane];
    float dui = u_c * i_c;

    // wave-wide butterfly reduction of both scalars
    #pragma unroll
    for (int off = 32; off >= 1; off >>= 1) {
        ds  += __shfl_xor(ds,  off, 64);
        dui += __shfl_xor(dui, off, 64);
    }

    if (lane == 0) {
        const float norm = (n > 0) ? sqrtf((float)n) : 1.0f;
        out[b] = dui + ds / norm + user_bias[user] + item_bias[item]
               + global_bias[0];
    }
}

extern "C" void kernel_launch(void* const* d_in, const int* in_sizes, int n_in,
                              void* d_out, int out_size, void* d_ws, size_t ws_size,
                              hipStream_t stream) {
    const int*   user_ids      = (const int*)  d_in[0];
    const int*   item_ids      = (const int*)  d_in[1];
    const int*   offsets       = (const int*)  d_in[2];
    const int*   flat_implicit = (const int*)  d_in[3];
    const float* user_emb      = (const float*)d_in[4];
    const float* item_emb      = (const float*)d_in[5];
    const float* imp_emb       = (const float*)d_in[6];
    const float* user_bias     = (const float*)d_in[7];
    const float* item_bias     = (const float*)d_in[8];
    const float* global_bias   = (const float*)d_in[9];
    float* out = (float*)d_out;

    const int B = in_sizes[0];
    const int N = in_sizes[3];

    const int grid = (B + WAVES_PER_BLOCK - 1) / WAVES_PER_BLOCK;
    svdpp_kernel<<<grid, WAVES_PER_BLOCK * 64, 0, stream>>>(
        user_ids, item_ids, offsets, flat_implicit,
        user_emb, item_emb, imp_emb,
        user_bias, item_bias, global_bias,
        out, B, N);
}